// Round 4
// baseline (309.680 us; speedup 1.0000x reference)
//
#include <hip/hip_runtime.h>

// ---------------------------------------------------------------------------
// Attention_42674795053784 : cross-attention forward on MI355X (gfx950)
// R11: fix gemm_qkv LDS over-allocation — GEMM_MAIN_LOOP's __shared__ arrays
//      were declared inside the macro, so the Q-branch + KV-branch double
//      instantiation statically allocated 64 KB/block (2 blocks/CU, 18.9%
//      occupancy). Shared tiles are now declared ONCE at kernel scope and
//      passed in: 32 KB/block -> up to 5 blocks/CU. No numeric changes.
//      attn keeps the R9 double-buffered pipeline.
// ---------------------------------------------------------------------------

typedef __bf16 bf16_t;
typedef __bf16 bf16x8 __attribute__((ext_vector_type(8)));
typedef float  f32x4  __attribute__((ext_vector_type(4)));

#define DIMM   1024
#define NHEAD  16
#define HDIM   64
#define NB     4
#define SEQ    2048
#define NROWS  (NB * SEQ)             // 8192
#define RMS_EPS 1.1920929e-07f
#define LOG2_10000_DIV32 0.4152410118609203f
// q scale: (1/8) * log2(e) so attn can use exp2 directly
#define QSCALE 0.18033688011112042f

// async global->LDS, 16B per lane; lds dest = base + lane*16 (wave-uniform base)
__device__ __forceinline__ void async16(const bf16_t* g, bf16_t* l) {
    __builtin_amdgcn_global_load_lds(
        (const __attribute__((address_space(1))) void*)g,
        (__attribute__((address_space(3))) void*)l, 16, 0, 0);
}

// --------------------------------------------------------------------------
// prep: fp32->bf16 casts (blocks 0..8191) + 3 weight transposes (8192..12287)
// --------------------------------------------------------------------------
__global__ __launch_bounds__(256)
void prep(const float* __restrict__ tgt, const float* __restrict__ src,
          bf16_t* __restrict__ tgtb, bf16_t* __restrict__ srcb,
          const float* __restrict__ Wq, const float* __restrict__ Wkv,
          const float* __restrict__ Wo, bf16_t* __restrict__ Wq_t,
          bf16_t* __restrict__ Wkv_t, bf16_t* __restrict__ Wo_t)
{
    __shared__ float t[32][33];
    int bid = blockIdx.x;
    if (bid < 8192) {                       // elementwise cast
        const float* x;
        bf16_t* y;
        if (bid < 4096) { x = tgt; y = tgtb; }
        else            { bid -= 4096; x = src; y = srcb; }
        const size_t i = ((size_t)bid * 256 + threadIdx.x) * 8;
        float4 f0 = ((const float4*)(x + i))[0];
        float4 f1 = ((const float4*)(x + i))[1];
        bf16_t v[8];
        v[0] = (bf16_t)f0.x; v[1] = (bf16_t)f0.y; v[2] = (bf16_t)f0.z; v[3] = (bf16_t)f0.w;
        v[4] = (bf16_t)f1.x; v[5] = (bf16_t)f1.y; v[6] = (bf16_t)f1.z; v[7] = (bf16_t)f1.w;
        *(int4*)(y + i) = *(int4*)v;
        return;
    }
    bid -= 8192;                            // weight transpose
    const float* W; bf16_t* Wt; int N, nx;
    if (bid < 1024)      { W = Wq;  Wt = Wq_t;  N = 1024; nx = 32; }
    else if (bid < 3072) { bid -= 1024; W = Wkv; Wt = Wkv_t; N = 2048; nx = 64; }
    else                 { bid -= 3072; W = Wo;  Wt = Wo_t;  N = 1024; nx = 32; }
    const int K  = 1024;
    const int n0 = (bid % nx) * 32;
    const int k0 = (bid / nx) * 32;
    const int tx = threadIdx.x & 31;
    const int ty = threadIdx.x >> 5;
#pragma unroll
    for (int i = ty; i < 32; i += 8)
        t[i][tx] = W[(size_t)(k0 + i) * N + n0 + tx];
    __syncthreads();
#pragma unroll
    for (int i = ty; i < 32; i += 8)
        Wt[(size_t)(n0 + i) * K + k0 + tx] = (bf16_t)t[tx][i];
}

// --------------------------------------------------------------------------
// Shared GEMM main loop (m97-style): acc = A[128 rows] * Bt[128 rows]^T
// __shared__ tiles are DECLARED BY THE CALLER (exactly once per kernel) so
// multi-branch kernels don't double-allocate LDS.
// --------------------------------------------------------------------------
#define GEMM_MAIN_LOOP(A_, Bt_, K_, As, Bs)                                   \
    const int tid  = threadIdx.x;                                             \
    const int lane = tid & 63;                                                \
    const int wave = tid >> 6;                                                \
    const int wm   = (wave >> 1) * 64;                                        \
    const int wn   = (wave & 1) * 64;                                         \
    const int lr   = lane & 15;                                               \
    const int quad = lane >> 4;                                               \
    {                                                                         \
        const int srow = lane >> 3;                                           \
        const int sslot = lane & 7;                                           \
        size_t aoff[4], boff[4];                                              \
        bf16_t *alp[4], *blp[4];                                              \
        _Pragma("unroll")                                                     \
        for (int t = 0; t < 4; ++t) {                                         \
            const int rb = wave * 32 + t * 8;                                 \
            const int r  = rb + srow;                                         \
            const int g  = sslot ^ (r & 7);                                   \
            aoff[t] = (size_t)(bm + r) * (K_) + g * 8;                        \
            boff[t] = (size_t)(bn + r) * (K_) + g * 8;                        \
            alp[t]  = (As) + rb * 64;                                         \
            blp[t]  = (Bs) + rb * 64;                                         \
        }                                                                     \
        for (int k0 = 0; k0 < (K_); k0 += 64) {                               \
            _Pragma("unroll")                                                 \
            for (int t = 0; t < 4; ++t) {                                     \
                async16((A_)  + aoff[t] + k0, alp[t]);                        \
                async16((Bt_) + boff[t] + k0, blp[t]);                        \
            }                                                                 \
            __syncthreads();                                                  \
            _Pragma("unroll")                                                 \
            for (int ks = 0; ks < 2; ++ks) {                                  \
                bf16x8 af[4], bfr[4];                                         \
                _Pragma("unroll")                                             \
                for (int i = 0; i < 4; ++i)                                   \
                    af[i] = *(const bf16x8*)&(As)[(wm + i * 16 + lr) * 64 +   \
                                (((ks * 4 + quad) ^ (lr & 7)) * 8)];          \
                _Pragma("unroll")                                             \
                for (int j = 0; j < 4; ++j)                                   \
                    bfr[j] = *(const bf16x8*)&(Bs)[(wn + j * 16 + lr) * 64 +  \
                                (((ks * 4 + quad) ^ (lr & 7)) * 8)];          \
                _Pragma("unroll")                                             \
                for (int i = 0; i < 4; ++i)                                   \
                    _Pragma("unroll")                                         \
                    for (int j = 0; j < 4; ++j)                               \
                        acc[i][j] = __builtin_amdgcn_mfma_f32_16x16x32_bf16(  \
                            af[i], bfr[j], acc[i][j], 0, 0, 0);               \
            }                                                                 \
            __syncthreads();                                                  \
        }                                                                     \
    }

// Fused per-head RMSNorm + RoPE epilogue (wave's 64 cols == one head).
__device__ __forceinline__ void norm_rope_store(
    f32x4 acc[4][4], const int* __restrict__ pos, const float* __restrict__ w,
    bf16_t* __restrict__ dstbase, int bm, int wm, int head,
    int lr, int quad, float oscale)
{
    float w0 = w[lr], w1 = w[16 + lr], w2 = w[32 + lr], w3 = w[48 + lr];
    const float invf0 = exp2f(-(float)lr * LOG2_10000_DIV32);
    const float invf1 = exp2f(-(float)(lr + 16) * LOG2_10000_DIV32);
#pragma unroll
    for (int i = 0; i < 4; ++i) {
        const int gr = bm + wm + i * 16 + quad * 4;
        int4 pos4 = *(const int4*)&pos[gr];
#pragma unroll
        for (int rg = 0; rg < 4; ++rg) {
            float x0 = acc[i][0][rg], x1 = acc[i][1][rg];
            float x2 = acc[i][2][rg], x3 = acc[i][3][rg];
            float ssum = x0 * x0 + x1 * x1 + x2 * x2 + x3 * x3;
#pragma unroll
            for (int off = 1; off < 16; off <<= 1)
                ssum += __shfl_xor(ssum, off, 64);
            const float rn = rsqrtf(ssum * (1.f / 64.f) + RMS_EPS);
            x0 *= rn * w0; x1 *= rn * w1; x2 *= rn * w2; x3 *= rn * w3;
            const float p  = (float)((&pos4.x)[rg]);
            const float a0 = p * invf0, a1 = p * invf1;
            const float s0 = __sinf(a0), c0 = __cosf(a0);
            const float s1 = __sinf(a1), c1 = __cosf(a1);
            const int row = gr + rg;
            const int bb = row >> 11, si = row & 2047;
            bf16_t* dst = dstbase +
                ((size_t)(bb * NHEAD + head) * SEQ + si) * HDIM;
            dst[lr]      = (bf16_t)((x0 * c0 - x2 * s0) * oscale);
            dst[16 + lr] = (bf16_t)((x1 * c1 - x3 * s1) * oscale);
            dst[32 + lr] = (bf16_t)((x2 * c0 + x0 * s0) * oscale);
            dst[48 + lr] = (bf16_t)((x3 * c1 + x1 * s1) * oscale);
        }
    }
}

// --------------------------------------------------------------------------
// Merged Q + KV projection.  Blocks 0..511: Q GEMM (fused norm+rope, QSCALE).
// Blocks 512..1535: KV GEMM (K: fused norm+rope; V: m-permuted direct to vT).
// V permutation (R3 16x16 PV B-frag order), self-similar within 32-blocks:
//   m = ksm*32 + bit4*16 + quad*4 + r  lives at  p = ksm*32 + quad*8 + bit4*4 + r
// --------------------------------------------------------------------------
__global__ __launch_bounds__(256)
void gemm_qkv(const bf16_t* __restrict__ tgtb, const bf16_t* __restrict__ srcb,
              const bf16_t* __restrict__ Wq_t, const bf16_t* __restrict__ Wkv_t,
              const int* __restrict__ tpos, const int* __restrict__ spos,
              const float* __restrict__ qw, const float* __restrict__ kw,
              bf16_t* __restrict__ qb, bf16_t* __restrict__ kbuf,
              bf16_t* __restrict__ vT)
{
    __shared__ bf16_t As[128 * 64];      // single 32 KB allocation for BOTH
    __shared__ bf16_t Bs[128 * 64];      // branches (was 64 KB: 2x macro)
    const int bid = blockIdx.x;
    if (bid < 512) {                         // ---- Q projection ----
        const int bm = (bid >> 3) * 128;
        const int bn = (bid & 7) * 128;
        f32x4 acc[4][4] = {};
        GEMM_MAIN_LOOP(tgtb, Wq_t, 1024, As, Bs)
        const int head = (bn + wn) >> 6;
        norm_rope_store(acc, tpos, qw, qb, bm, wm, head, lr, quad, QSCALE);
    } else {                                 // ---- KV projection ----
        const int t2 = bid - 512;
        const int bm = (t2 >> 4) * 128;
        const int bn = (t2 & 15) * 128;
        f32x4 acc[4][4] = {};
        GEMM_MAIN_LOOP(srcb, Wkv_t, 1024, As, Bs)
        if (bn < 1024) {                     // K proj
            const int head = (bn + wn) >> 6;
            norm_rope_store(acc, spos, kw, kbuf, bm, wm, head, lr, quad, 1.0f);
        } else {                             // V proj, m-permuted to vT (R3 order)
#pragma unroll
            for (int i = 0; i < 4; ++i) {
                const int M0 = bm + wm + i * 16;
                const int b  = M0 >> 11;
                const int mB = M0 & 2047;
                const int chunkbase = mB & ~127;
                const int ksm  = (mB >> 5) & 3;
                const int bit4 = (mB >> 4) & 1;
                const int pbase = (ksm * 4 + quad) * 8 + bit4 * 4;
#pragma unroll
                for (int j = 0; j < 4; ++j) {
                    const int c = bn + wn + j * 16 + lr - 1024;
                    const int h = c >> 6;
                    const int d = c & 63;
                    bf16_t pk[4];
#pragma unroll
                    for (int rg = 0; rg < 4; ++rg) pk[rg] = (bf16_t)acc[i][j][rg];
                    bf16_t* dst = vT + ((size_t)(b * NHEAD + h) * HDIM + d) * SEQ
                                  + chunkbase + pbase;
                    *(int2*)dst = *(int2*)pk;
                }
            }
        }
    }
}

// --------------------------------------------------------------------------
// Output projection GEMM (fp32 out).
// --------------------------------------------------------------------------
__global__ __launch_bounds__(256)
void gemm_o(const bf16_t* __restrict__ A, const bf16_t* __restrict__ Bt,
            float* __restrict__ Cp)
{
    __shared__ bf16_t As[128 * 64];
    __shared__ bf16_t Bs[128 * 64];
    const int bm = blockIdx.y * 128;
    const int bn = blockIdx.x * 128;
    f32x4 acc[4][4] = {};
    GEMM_MAIN_LOOP(A, Bt, 1024, As, Bs)
#pragma unroll
    for (int i = 0; i < 4; ++i)
#pragma unroll
        for (int j = 0; j < 4; ++j) {
            const int r0 = bm + wm + i * 16 + quad * 4;
            const int c  = bn + wn + j * 16 + lr;
#pragma unroll
            for (int rg = 0; rg < 4; ++rg)
                Cp[(size_t)(r0 + rg) * 1024 + c] = acc[i][j][rg];
        }
}

// --------------------------------------------------------------------------
// Flash attention (R9/R10): fixed-max softmax (exp2), register-resident P,
// 16x16x32 MFMAs, 4 waves x 32 q-rows, XCD-aware 1-D grid.
// KVBLK=64, double-buffered Ks/Vs (32 KB total), STAGE(next)->COMPUTE(cur).
// --------------------------------------------------------------------------
__global__ __launch_bounds__(256, 4)
void attn(const bf16_t* __restrict__ q, const bf16_t* __restrict__ k,
          const bf16_t* __restrict__ vT, bf16_t* __restrict__ xo)
{
    __shared__ bf16_t Ks[2][64 * 64];     // [buf][m][d], XOR-swizzled (8 slots)
    __shared__ bf16_t Vs[2][64 * 64];     // [buf][d][m'], XOR-swizzled (8 slots)

    // swizzled decode: bid = xcd + 128*(grp&7) + 8*qx, grp>>3 == xcd
    const int bid = blockIdx.x;
    const int w   = bid >> 3;
    const int grp = (bid & 7) * 8 + (w >> 4);   // 0..63 = b*16+h
    const int q0  = (w & 15) * 128;
    const int h   = grp & 15;
    const int b   = grp >> 4;
    const int bh  = b * NHEAD + h;

    const int tid  = threadIdx.x;
    const int lane = tid & 63;
    const int wv   = tid >> 6;
    const int lr   = lane & 15;
    const int quad = lane >> 4;

    const bf16_t* kb = k  + (size_t)bh * SEQ * HDIM;
    const bf16_t* vb = vT + (size_t)bh * HDIM * SEQ;

    // Q fragments (B-operand), 2 q-tiles x 2 d-halves
    bf16x8 aq[2][2];
#pragma unroll
    for (int t = 0; t < 2; ++t) {
        const bf16_t* qp = q + ((size_t)bh * SEQ + q0 + wv * 32 + t * 16 + lr) * HDIM;
        aq[t][0] = *(const bf16x8*)(qp + quad * 8);
        aq[t][1] = *(const bf16x8*)(qp + 32 + quad * 8);
    }

    // cooperative staging: 2 K-DMAs + 2 V-DMAs per wave per 64-chunk.
    size_t koff[2], voff[2];
    int lbase[2];
#pragma unroll
    for (int s = 0; s < 2; ++s) {
        const int rb = wv * 16 + s * 8;
        const int r  = rb + (lane >> 3);
        const int g  = (lane & 7) ^ (r & 7);    // pre-swizzled global slot
        koff[s]  = (size_t)r * HDIM + g * 8;
        voff[s]  = (size_t)r * SEQ  + g * 8;
        lbase[s] = rb * 64;
    }

    // loop-invariant LDS read bases, both buffers (all reads = base + imm)
    const bf16_t* kbase[2][2];
    const bf16_t* vbase[2][2];
#pragma unroll
    for (int bf = 0; bf < 2; ++bf)
#pragma unroll
        for (int x = 0; x < 2; ++x) {
            const int sw = (((x * 4 + quad) ^ (lr & 7)) * 8);
            kbase[bf][x] = &Ks[bf][lr * 64 + sw];
            vbase[bf][x] = &Vs[bf][lr * 64 + sw];
        }

    f32x4 zero4 = {0.f, 0.f, 0.f, 0.f};
    f32x4 o[2][4];                        // [q-tile][d-tile]
    float lsum[2] = {0.f, 0.f};
#pragma unroll
    for (int t = 0; t < 2; ++t)
#pragma unroll
        for (int dt = 0; dt < 4; ++dt) o[t][dt] = zero4;

#define STAGE(NB_, M0) do {                                                  \
    const size_t _kg = (size_t)(M0) * HDIM;                                  \
    async16(kb + _kg + koff[0], &Ks[NB_][lbase[0]]);                         \
    async16(kb + _kg + koff[1], &Ks[NB_][lbase[1]]);                         \
    async16(vb + (M0) + voff[0], &Vs[NB_][lbase[0]]);                        \
    async16(vb + (M0) + voff[1], &Vs[NB_][lbase[1]]);                        \
} while (0)

#define COMPUTE(CB) do {                                                     \
    _Pragma("unroll")                                                        \
    for (int ksm = 0; ksm < 2; ++ksm) {                                      \
        bf16x8 bp0, bp1;                                                     \
        _Pragma("unroll")                                                    \
        for (int half = 0; half < 2; ++half) {                               \
            const int mt = ksm * 2 + half;                                   \
            f32x4 s0 = zero4, s1 = zero4;                                    \
            bf16x8 ak0 = *(const bf16x8*)(kbase[CB][0] + mt * 1024);         \
            s0 = __builtin_amdgcn_mfma_f32_16x16x32_bf16(ak0, aq[0][0], s0, 0, 0, 0); \
            s1 = __builtin_amdgcn_mfma_f32_16x16x32_bf16(ak0, aq[1][0], s1, 0, 0, 0); \
            bf16x8 ak1 = *(const bf16x8*)(kbase[CB][1] + mt * 1024);         \
            s0 = __builtin_amdgcn_mfma_f32_16x16x32_bf16(ak1, aq[0][1], s0, 0, 0, 0); \
            s1 = __builtin_amdgcn_mfma_f32_16x16x32_bf16(ak1, aq[1][1], s1, 0, 0, 0); \
            _Pragma("unroll")                                                \
            for (int r = 0; r < 4; ++r) {                                    \
                const float p0 = __builtin_amdgcn_exp2f(s0[r]);              \
                const float p1 = __builtin_amdgcn_exp2f(s1[r]);              \
                lsum[0] += p0; lsum[1] += p1;                                \
                bp0[half * 4 + r] = (bf16_t)p0;                              \
                bp1[half * 4 + r] = (bf16_t)p1;                              \
            }                                                                \
        }                                                                    \
        _Pragma("unroll")                                                    \
        for (int dt = 0; dt < 4; ++dt) {                                     \
            bf16x8 av = *(const bf16x8*)(vbase[CB][ksm] + dt * 1024);        \
            o[0][dt] = __builtin_amdgcn_mfma_f32_16x16x32_bf16(av, bp0, o[0][dt], 0, 0, 0); \
            o[1][dt] = __builtin_amdgcn_mfma_f32_16x16x32_bf16(av, bp1, o[1][dt], 0, 0, 0); \
        }                                                                    \
    }                                                                        \
} while (0)

    // prologue: stage chunk 0 into buf 0 (only exposed load of the kernel)
    STAGE(0, 0);
    __syncthreads();

    for (int t0 = 0; t0 < 32; t0 += 2) {
        STAGE(1, (t0 + 1) * 64);            // fly under COMPUTE(0)
        COMPUTE(0);
        __syncthreads();                    // drains long-since-landed DMAs
        STAGE(0, (((t0 + 2) & 31)) * 64);   // wrap on last iter (harmless reload)
        COMPUTE(1);
        __syncthreads();
    }

#undef STAGE
#undef COMPUTE

    // row-sum: per-lane partial (q=lr) reduced across the 4 quads
#pragma unroll
    for (int t = 0; t < 2; ++t) {
        lsum[t] += __shfl_xor(lsum[t], 16, 64);
        lsum[t] += __shfl_xor(lsum[t], 32, 64);
        lsum[t] = 1.f / lsum[t];
    }

    // O^T C/D: row=d=quad*4+rg, col=q=lr -> 4 consecutive d: 8B stores
#pragma unroll
    for (int t = 0; t < 2; ++t)
#pragma unroll
        for (int dt = 0; dt < 4; ++dt) {
            bf16_t pk[4];
#pragma unroll
            for (int rg = 0; rg < 4; ++rg)
                pk[rg] = (bf16_t)(o[t][dt][rg] * lsum[t]);
            bf16_t* dst = xo + ((size_t)b * SEQ + q0 + wv * 32 + t * 16 + lr) * DIMM
                          + h * HDIM + dt * 16 + quad * 4;
            *(int2*)dst = *(int2*)pk;
        }
}

// --------------------------------------------------------------------------
extern "C" void kernel_launch(void* const* d_in, const int* in_sizes, int n_in,
                              void* d_out, int out_size, void* d_ws, size_t ws_size,
                              hipStream_t stream)
{
    const float* tgt  = (const float*)d_in[0];
    const float* src  = (const float*)d_in[1];
    const int*   tpos = (const int*)d_in[2];
    const int*   spos = (const int*)d_in[3];
    const float* Wq   = (const float*)d_in[4];
    const float* Wkv  = (const float*)d_in[5];
    const float* Wo   = (const float*)d_in[6];
    const float* qw   = (const float*)d_in[7];
    const float* kw   = (const float*)d_in[8];
    float* out = (float*)d_out;

    // workspace layout — 88 MB with buffer reuse
    char* ws = (char*)d_ws;
    const size_t MB = 1024 * 1024;
    bf16_t* Wq_t  = (bf16_t*)(ws + 0 * MB);    //  2 MB
    bf16_t* Wkv_t = (bf16_t*)(ws + 2 * MB);    //  4 MB
    bf16_t* Wo_t  = (bf16_t*)(ws + 6 * MB);    //  2 MB
    bf16_t* tgtb  = (bf16_t*)(ws + 8 * MB);    // 16 MB
    bf16_t* srcb  = (bf16_t*)(ws + 24 * MB);   // 16 MB (dead after gemm_qkv)
    bf16_t* xb    = (bf16_t*)(ws + 24 * MB);   //   ... reused: attn out
    bf16_t* qb    = (bf16_t*)(ws + 40 * MB);   // 16 MB  [b,h,n,64]
    bf16_t* kbuf  = (bf16_t*)(ws + 56 * MB);   // 16 MB  [b,h,m,64]
    bf16_t* vT    = (bf16_t*)(ws + 72 * MB);   // 16 MB  [b,h,64,m'] permuted

    // casts + weight transposes (one launch)
    prep<<<12288, 256, 0, stream>>>(tgt, src, tgtb, srcb,
                                    Wq, Wkv, Wo, Wq_t, Wkv_t, Wo_t);

    // Q + KV projections with fused norm/rope + V-permute epilogues (one launch)
    gemm_qkv<<<1536, 256, 0, stream>>>(tgtb, srcb, Wq_t, Wkv_t,
                                       tpos, spos, qw, kw, qb, kbuf, vT);

    // flash attention (R9/R10 double-buffered pipeline + XCD-aware swizzle)
    attn<<<1024, 256, 0, stream>>>(qb, kbuf, vT, xb);

    // output projection (fp32 out)
    gemm_o<<<dim3(8, 64), 256, 0, stream>>>(xb, Wo_t, out);
}

// Round 5
// 298.829 us; speedup vs baseline: 1.0363x; 1.0363x over previous
//
#include <hip/hip_runtime.h>

// ---------------------------------------------------------------------------
// Attention_42674795053784 : cross-attention forward on MI355X (gfx950)
// R12: gemm residency + L2 locality.
//  - Diagnosis: VGPR_Count=112 excludes the 64-AGPR accumulator; unified
//    gfx950 file -> ~176 regs/wave -> 2 blocks/CU (matches 19% occupancy,
//    and why the R11 LDS fix changed nothing).
//  - __launch_bounds__(256,4) on gemm_qkv/gemm_o forces <=128 regs/wave
//    (4 blocks/CU); staging offsets shrunk to 32-bit to fit.
//  - XCD-colocating swizzle on both GEMM grids (A-panel + B reuse in L2).
//  - prep / attn unchanged.
// ---------------------------------------------------------------------------

typedef __bf16 bf16_t;
typedef __bf16 bf16x8 __attribute__((ext_vector_type(8)));
typedef float  f32x4  __attribute__((ext_vector_type(4)));

#define DIMM   1024
#define NHEAD  16
#define HDIM   64
#define NB     4
#define SEQ    2048
#define NROWS  (NB * SEQ)             // 8192
#define RMS_EPS 1.1920929e-07f
#define LOG2_10000_DIV32 0.4152410118609203f
// q scale: (1/8) * log2(e) so attn can use exp2 directly
#define QSCALE 0.18033688011112042f

// async global->LDS, 16B per lane; lds dest = base + lane*16 (wave-uniform base)
__device__ __forceinline__ void async16(const bf16_t* g, bf16_t* l) {
    __builtin_amdgcn_global_load_lds(
        (const __attribute__((address_space(1))) void*)g,
        (__attribute__((address_space(3))) void*)l, 16, 0, 0);
}

// --------------------------------------------------------------------------
// prep: fp32->bf16 casts (blocks 0..8191) + 3 weight transposes (8192..12287)
// --------------------------------------------------------------------------
__global__ __launch_bounds__(256)
void prep(const float* __restrict__ tgt, const float* __restrict__ src,
          bf16_t* __restrict__ tgtb, bf16_t* __restrict__ srcb,
          const float* __restrict__ Wq, const float* __restrict__ Wkv,
          const float* __restrict__ Wo, bf16_t* __restrict__ Wq_t,
          bf16_t* __restrict__ Wkv_t, bf16_t* __restrict__ Wo_t)
{
    __shared__ float t[32][33];
    int bid = blockIdx.x;
    if (bid < 8192) {                       // elementwise cast
        const float* x;
        bf16_t* y;
        if (bid < 4096) { x = tgt; y = tgtb; }
        else            { bid -= 4096; x = src; y = srcb; }
        const size_t i = ((size_t)bid * 256 + threadIdx.x) * 8;
        float4 f0 = ((const float4*)(x + i))[0];
        float4 f1 = ((const float4*)(x + i))[1];
        bf16_t v[8];
        v[0] = (bf16_t)f0.x; v[1] = (bf16_t)f0.y; v[2] = (bf16_t)f0.z; v[3] = (bf16_t)f0.w;
        v[4] = (bf16_t)f1.x; v[5] = (bf16_t)f1.y; v[6] = (bf16_t)f1.z; v[7] = (bf16_t)f1.w;
        *(int4*)(y + i) = *(int4*)v;
        return;
    }
    bid -= 8192;                            // weight transpose
    const float* W; bf16_t* Wt; int N, nx;
    if (bid < 1024)      { W = Wq;  Wt = Wq_t;  N = 1024; nx = 32; }
    else if (bid < 3072) { bid -= 1024; W = Wkv; Wt = Wkv_t; N = 2048; nx = 64; }
    else                 { bid -= 3072; W = Wo;  Wt = Wo_t;  N = 1024; nx = 32; }
    const int K  = 1024;
    const int n0 = (bid % nx) * 32;
    const int k0 = (bid / nx) * 32;
    const int tx = threadIdx.x & 31;
    const int ty = threadIdx.x >> 5;
#pragma unroll
    for (int i = ty; i < 32; i += 8)
        t[i][tx] = W[(size_t)(k0 + i) * N + n0 + tx];
    __syncthreads();
#pragma unroll
    for (int i = ty; i < 32; i += 8)
        Wt[(size_t)(n0 + i) * K + k0 + tx] = (bf16_t)t[tx][i];
}

// --------------------------------------------------------------------------
// Shared GEMM main loop (m97-style): acc = A[128 rows] * Bt[128 rows]^T
// __shared__ tiles are DECLARED BY THE CALLER (exactly once per kernel).
// Staging offsets are 32-bit (max 16 MB) so loads lower to sbase+voffset.
// --------------------------------------------------------------------------
#define GEMM_MAIN_LOOP(A_, Bt_, K_, As, Bs)                                   \
    const int tid  = threadIdx.x;                                             \
    const int lane = tid & 63;                                                \
    const int wave = tid >> 6;                                                \
    const int wm   = (wave >> 1) * 64;                                        \
    const int wn   = (wave & 1) * 64;                                         \
    const int lr   = lane & 15;                                               \
    const int quad = lane >> 4;                                               \
    {                                                                         \
        const int srow = lane >> 3;                                           \
        const int sslot = lane & 7;                                           \
        unsigned aoff[4], boff[4];                                            \
        bf16_t *alp[4], *blp[4];                                              \
        _Pragma("unroll")                                                     \
        for (int t = 0; t < 4; ++t) {                                         \
            const int rb = wave * 32 + t * 8;                                 \
            const int r  = rb + srow;                                         \
            const int g  = sslot ^ (r & 7);                                   \
            aoff[t] = (unsigned)(bm + r) * (K_) + g * 8;                      \
            boff[t] = (unsigned)(bn + r) * (K_) + g * 8;                      \
            alp[t]  = (As) + rb * 64;                                         \
            blp[t]  = (Bs) + rb * 64;                                         \
        }                                                                     \
        for (int k0 = 0; k0 < (K_); k0 += 64) {                               \
            _Pragma("unroll")                                                 \
            for (int t = 0; t < 4; ++t) {                                     \
                async16((A_)  + (aoff[t] + k0), alp[t]);                      \
                async16((Bt_) + (boff[t] + k0), blp[t]);                      \
            }                                                                 \
            __syncthreads();                                                  \
            _Pragma("unroll")                                                 \
            for (int ks = 0; ks < 2; ++ks) {                                  \
                bf16x8 af[4], bfr[4];                                         \
                _Pragma("unroll")                                             \
                for (int i = 0; i < 4; ++i)                                   \
                    af[i] = *(const bf16x8*)&(As)[(wm + i * 16 + lr) * 64 +   \
                                (((ks * 4 + quad) ^ (lr & 7)) * 8)];          \
                _Pragma("unroll")                                             \
                for (int j = 0; j < 4; ++j)                                   \
                    bfr[j] = *(const bf16x8*)&(Bs)[(wn + j * 16 + lr) * 64 +  \
                                (((ks * 4 + quad) ^ (lr & 7)) * 8)];          \
                _Pragma("unroll")                                             \
                for (int i = 0; i < 4; ++i)                                   \
                    _Pragma("unroll")                                         \
                    for (int j = 0; j < 4; ++j)                               \
                        acc[i][j] = __builtin_amdgcn_mfma_f32_16x16x32_bf16(  \
                            af[i], bfr[j], acc[i][j], 0, 0, 0);               \
            }                                                                 \
            __syncthreads();                                                  \
        }                                                                     \
    }

// Fused per-head RMSNorm + RoPE epilogue (wave's 64 cols == one head).
__device__ __forceinline__ void norm_rope_store(
    f32x4 acc[4][4], const int* __restrict__ pos, const float* __restrict__ w,
    bf16_t* __restrict__ dstbase, int bm, int wm, int head,
    int lr, int quad, float oscale)
{
    float w0 = w[lr], w1 = w[16 + lr], w2 = w[32 + lr], w3 = w[48 + lr];
    const float invf0 = exp2f(-(float)lr * LOG2_10000_DIV32);
    const float invf1 = exp2f(-(float)(lr + 16) * LOG2_10000_DIV32);
#pragma unroll
    for (int i = 0; i < 4; ++i) {
        const int gr = bm + wm + i * 16 + quad * 4;
        int4 pos4 = *(const int4*)&pos[gr];
#pragma unroll
        for (int rg = 0; rg < 4; ++rg) {
            float x0 = acc[i][0][rg], x1 = acc[i][1][rg];
            float x2 = acc[i][2][rg], x3 = acc[i][3][rg];
            float ssum = x0 * x0 + x1 * x1 + x2 * x2 + x3 * x3;
#pragma unroll
            for (int off = 1; off < 16; off <<= 1)
                ssum += __shfl_xor(ssum, off, 64);
            const float rn = rsqrtf(ssum * (1.f / 64.f) + RMS_EPS);
            x0 *= rn * w0; x1 *= rn * w1; x2 *= rn * w2; x3 *= rn * w3;
            const float p  = (float)((&pos4.x)[rg]);
            const float a0 = p * invf0, a1 = p * invf1;
            const float s0 = __sinf(a0), c0 = __cosf(a0);
            const float s1 = __sinf(a1), c1 = __cosf(a1);
            const int row = gr + rg;
            const int bb = row >> 11, si = row & 2047;
            bf16_t* dst = dstbase +
                ((size_t)(bb * NHEAD + head) * SEQ + si) * HDIM;
            dst[lr]      = (bf16_t)((x0 * c0 - x2 * s0) * oscale);
            dst[16 + lr] = (bf16_t)((x1 * c1 - x3 * s1) * oscale);
            dst[32 + lr] = (bf16_t)((x2 * c0 + x0 * s0) * oscale);
            dst[48 + lr] = (bf16_t)((x3 * c1 + x1 * s1) * oscale);
        }
    }
}

// --------------------------------------------------------------------------
// Merged Q + KV projection.  Logical blocks 0..511: Q GEMM (fused norm+rope).
// Logical 512..1535: KV GEMM (K: norm+rope; V: m-permuted direct to vT).
// HW blockIdx is XCD-swizzled: 1536 = 8 XCDs x 192 contiguous logical blocks,
// so the 8-16 blocks sharing an A-panel land on ONE XCD's L2.
// --------------------------------------------------------------------------
__global__ __launch_bounds__(256, 4)
void gemm_qkv(const bf16_t* __restrict__ tgtb, const bf16_t* __restrict__ srcb,
              const bf16_t* __restrict__ Wq_t, const bf16_t* __restrict__ Wkv_t,
              const int* __restrict__ tpos, const int* __restrict__ spos,
              const float* __restrict__ qw, const float* __restrict__ kw,
              bf16_t* __restrict__ qb, bf16_t* __restrict__ kbuf,
              bf16_t* __restrict__ vT)
{
    __shared__ bf16_t As[128 * 64];      // single 32 KB allocation, both branches
    __shared__ bf16_t Bs[128 * 64];
    const int raw = blockIdx.x;
    const int bid = (raw & 7) * 192 + (raw >> 3);   // XCD-colocating bijection
    if (bid < 512) {                         // ---- Q projection ----
        const int bm = (bid >> 3) * 128;
        const int bn = (bid & 7) * 128;
        f32x4 acc[4][4] = {};
        GEMM_MAIN_LOOP(tgtb, Wq_t, 1024, As, Bs)
        const int head = (bn + wn) >> 6;
        norm_rope_store(acc, tpos, qw, qb, bm, wm, head, lr, quad, QSCALE);
    } else {                                 // ---- KV projection ----
        const int t2 = bid - 512;
        const int bm = (t2 >> 4) * 128;
        const int bn = (t2 & 15) * 128;
        f32x4 acc[4][4] = {};
        GEMM_MAIN_LOOP(srcb, Wkv_t, 1024, As, Bs)
        if (bn < 1024) {                     // K proj
            const int head = (bn + wn) >> 6;
            norm_rope_store(acc, spos, kw, kbuf, bm, wm, head, lr, quad, 1.0f);
        } else {                             // V proj, m-permuted to vT (R3 order)
#pragma unroll
            for (int i = 0; i < 4; ++i) {
                const int M0 = bm + wm + i * 16;
                const int b  = M0 >> 11;
                const int mB = M0 & 2047;
                const int chunkbase = mB & ~127;
                const int ksm  = (mB >> 5) & 3;
                const int bit4 = (mB >> 4) & 1;
                const int pbase = (ksm * 4 + quad) * 8 + bit4 * 4;
#pragma unroll
                for (int j = 0; j < 4; ++j) {
                    const int c = bn + wn + j * 16 + lr - 1024;
                    const int h = c >> 6;
                    const int d = c & 63;
                    bf16_t pk[4];
#pragma unroll
                    for (int rg = 0; rg < 4; ++rg) pk[rg] = (bf16_t)acc[i][j][rg];
                    bf16_t* dst = vT + ((size_t)(b * NHEAD + h) * HDIM + d) * SEQ
                                  + chunkbase + pbase;
                    *(int2*)dst = *(int2*)pk;
                }
            }
        }
    }
}

// --------------------------------------------------------------------------
// Output projection GEMM (fp32 out). 1-D grid 512 = 8 XCDs x 64, swizzled.
// --------------------------------------------------------------------------
__global__ __launch_bounds__(256, 4)
void gemm_o(const bf16_t* __restrict__ A, const bf16_t* __restrict__ Bt,
            float* __restrict__ Cp)
{
    __shared__ bf16_t As[128 * 64];
    __shared__ bf16_t Bs[128 * 64];
    const int raw = blockIdx.x;
    const int swz = (raw & 7) * 64 + (raw >> 3);    // XCD-colocating bijection
    const int bm = (swz >> 3) * 128;
    const int bn = (swz & 7) * 128;
    f32x4 acc[4][4] = {};
    GEMM_MAIN_LOOP(A, Bt, 1024, As, Bs)
#pragma unroll
    for (int i = 0; i < 4; ++i)
#pragma unroll
        for (int j = 0; j < 4; ++j) {
            const int r0 = bm + wm + i * 16 + quad * 4;
            const int c  = bn + wn + j * 16 + lr;
#pragma unroll
            for (int rg = 0; rg < 4; ++rg)
                Cp[(size_t)(r0 + rg) * 1024 + c] = acc[i][j][rg];
        }
}

// --------------------------------------------------------------------------
// Flash attention (R9/R10): fixed-max softmax (exp2), register-resident P,
// 16x16x32 MFMAs, 4 waves x 32 q-rows, XCD-aware 1-D grid.
// KVBLK=64, double-buffered Ks/Vs (32 KB total), STAGE(next)->COMPUTE(cur).
// --------------------------------------------------------------------------
__global__ __launch_bounds__(256, 4)
void attn(const bf16_t* __restrict__ q, const bf16_t* __restrict__ k,
          const bf16_t* __restrict__ vT, bf16_t* __restrict__ xo)
{
    __shared__ bf16_t Ks[2][64 * 64];     // [buf][m][d], XOR-swizzled (8 slots)
    __shared__ bf16_t Vs[2][64 * 64];     // [buf][d][m'], XOR-swizzled (8 slots)

    // swizzled decode: bid = xcd + 128*(grp&7) + 8*qx, grp>>3 == xcd
    const int bid = blockIdx.x;
    const int w   = bid >> 3;
    const int grp = (bid & 7) * 8 + (w >> 4);   // 0..63 = b*16+h
    const int q0  = (w & 15) * 128;
    const int h   = grp & 15;
    const int b   = grp >> 4;
    const int bh  = b * NHEAD + h;

    const int tid  = threadIdx.x;
    const int lane = tid & 63;
    const int wv   = tid >> 6;
    const int lr   = lane & 15;
    const int quad = lane >> 4;

    const bf16_t* kb = k  + (size_t)bh * SEQ * HDIM;
    const bf16_t* vb = vT + (size_t)bh * HDIM * SEQ;

    // Q fragments (B-operand), 2 q-tiles x 2 d-halves
    bf16x8 aq[2][2];
#pragma unroll
    for (int t = 0; t < 2; ++t) {
        const bf16_t* qp = q + ((size_t)bh * SEQ + q0 + wv * 32 + t * 16 + lr) * HDIM;
        aq[t][0] = *(const bf16x8*)(qp + quad * 8);
        aq[t][1] = *(const bf16x8*)(qp + 32 + quad * 8);
    }

    // cooperative staging: 2 K-DMAs + 2 V-DMAs per wave per 64-chunk.
    size_t koff[2], voff[2];
    int lbase[2];
#pragma unroll
    for (int s = 0; s < 2; ++s) {
        const int rb = wv * 16 + s * 8;
        const int r  = rb + (lane >> 3);
        const int g  = (lane & 7) ^ (r & 7);    // pre-swizzled global slot
        koff[s]  = (size_t)r * HDIM + g * 8;
        voff[s]  = (size_t)r * SEQ  + g * 8;
        lbase[s] = rb * 64;
    }

    // loop-invariant LDS read bases, both buffers (all reads = base + imm)
    const bf16_t* kbase[2][2];
    const bf16_t* vbase[2][2];
#pragma unroll
    for (int bf = 0; bf < 2; ++bf)
#pragma unroll
        for (int x = 0; x < 2; ++x) {
            const int sw = (((x * 4 + quad) ^ (lr & 7)) * 8);
            kbase[bf][x] = &Ks[bf][lr * 64 + sw];
            vbase[bf][x] = &Vs[bf][lr * 64 + sw];
        }

    f32x4 zero4 = {0.f, 0.f, 0.f, 0.f};
    f32x4 o[2][4];                        // [q-tile][d-tile]
    float lsum[2] = {0.f, 0.f};
#pragma unroll
    for (int t = 0; t < 2; ++t)
#pragma unroll
        for (int dt = 0; dt < 4; ++dt) o[t][dt] = zero4;

#define STAGE(NB_, M0) do {                                                  \
    const size_t _kg = (size_t)(M0) * HDIM;                                  \
    async16(kb + _kg + koff[0], &Ks[NB_][lbase[0]]);                         \
    async16(kb + _kg + koff[1], &Ks[NB_][lbase[1]]);                         \
    async16(vb + (M0) + voff[0], &Vs[NB_][lbase[0]]);                        \
    async16(vb + (M0) + voff[1], &Vs[NB_][lbase[1]]);                        \
} while (0)

#define COMPUTE(CB) do {                                                     \
    _Pragma("unroll")                                                        \
    for (int ksm = 0; ksm < 2; ++ksm) {                                      \
        bf16x8 bp0, bp1;                                                     \
        _Pragma("unroll")                                                    \
        for (int half = 0; half < 2; ++half) {                               \
            const int mt = ksm * 2 + half;                                   \
            f32x4 s0 = zero4, s1 = zero4;                                    \
            bf16x8 ak0 = *(const bf16x8*)(kbase[CB][0] + mt * 1024);         \
            s0 = __builtin_amdgcn_mfma_f32_16x16x32_bf16(ak0, aq[0][0], s0, 0, 0, 0); \
            s1 = __builtin_amdgcn_mfma_f32_16x16x32_bf16(ak0, aq[1][0], s1, 0, 0, 0); \
            bf16x8 ak1 = *(const bf16x8*)(kbase[CB][1] + mt * 1024);         \
            s0 = __builtin_amdgcn_mfma_f32_16x16x32_bf16(ak1, aq[0][1], s0, 0, 0, 0); \
            s1 = __builtin_amdgcn_mfma_f32_16x16x32_bf16(ak1, aq[1][1], s1, 0, 0, 0); \
            _Pragma("unroll")                                                \
            for (int r = 0; r < 4; ++r) {                                    \
                const float p0 = __builtin_amdgcn_exp2f(s0[r]);              \
                const float p1 = __builtin_amdgcn_exp2f(s1[r]);              \
                lsum[0] += p0; lsum[1] += p1;                                \
                bp0[half * 4 + r] = (bf16_t)p0;                              \
                bp1[half * 4 + r] = (bf16_t)p1;                              \
            }                                                                \
        }                                                                    \
        _Pragma("unroll")                                                    \
        for (int dt = 0; dt < 4; ++dt) {                                     \
            bf16x8 av = *(const bf16x8*)(vbase[CB][ksm] + dt * 1024);        \
            o[0][dt] = __builtin_amdgcn_mfma_f32_16x16x32_bf16(av, bp0, o[0][dt], 0, 0, 0); \
            o[1][dt] = __builtin_amdgcn_mfma_f32_16x16x32_bf16(av, bp1, o[1][dt], 0, 0, 0); \
        }                                                                    \
    }                                                                        \
} while (0)

    // prologue: stage chunk 0 into buf 0 (only exposed load of the kernel)
    STAGE(0, 0);
    __syncthreads();

    for (int t0 = 0; t0 < 32; t0 += 2) {
        STAGE(1, (t0 + 1) * 64);            // fly under COMPUTE(0)
        COMPUTE(0);
        __syncthreads();                    // drains long-since-landed DMAs
        STAGE(0, (((t0 + 2) & 31)) * 64);   // wrap on last iter (harmless reload)
        COMPUTE(1);
        __syncthreads();
    }

#undef STAGE
#undef COMPUTE

    // row-sum: per-lane partial (q=lr) reduced across the 4 quads
#pragma unroll
    for (int t = 0; t < 2; ++t) {
        lsum[t] += __shfl_xor(lsum[t], 16, 64);
        lsum[t] += __shfl_xor(lsum[t], 32, 64);
        lsum[t] = 1.f / lsum[t];
    }

    // O^T C/D: row=d=quad*4+rg, col=q=lr -> 4 consecutive d: 8B stores
#pragma unroll
    for (int t = 0; t < 2; ++t)
#pragma unroll
        for (int dt = 0; dt < 4; ++dt) {
            bf16_t pk[4];
#pragma unroll
            for (int rg = 0; rg < 4; ++rg)
                pk[rg] = (bf16_t)(o[t][dt][rg] * lsum[t]);
            bf16_t* dst = xo + ((size_t)b * SEQ + q0 + wv * 32 + t * 16 + lr) * DIMM
                          + h * HDIM + dt * 16 + quad * 4;
            *(int2*)dst = *(int2*)pk;
        }
}

// --------------------------------------------------------------------------
extern "C" void kernel_launch(void* const* d_in, const int* in_sizes, int n_in,
                              void* d_out, int out_size, void* d_ws, size_t ws_size,
                              hipStream_t stream)
{
    const float* tgt  = (const float*)d_in[0];
    const float* src  = (const float*)d_in[1];
    const int*   tpos = (const int*)d_in[2];
    const int*   spos = (const int*)d_in[3];
    const float* Wq   = (const float*)d_in[4];
    const float* Wkv  = (const float*)d_in[5];
    const float* Wo   = (const float*)d_in[6];
    const float* qw   = (const float*)d_in[7];
    const float* kw   = (const float*)d_in[8];
    float* out = (float*)d_out;

    // workspace layout — 88 MB with buffer reuse
    char* ws = (char*)d_ws;
    const size_t MB = 1024 * 1024;
    bf16_t* Wq_t  = (bf16_t*)(ws + 0 * MB);    //  2 MB
    bf16_t* Wkv_t = (bf16_t*)(ws + 2 * MB);    //  4 MB
    bf16_t* Wo_t  = (bf16_t*)(ws + 6 * MB);    //  2 MB
    bf16_t* tgtb  = (bf16_t*)(ws + 8 * MB);    // 16 MB
    bf16_t* srcb  = (bf16_t*)(ws + 24 * MB);   // 16 MB (dead after gemm_qkv)
    bf16_t* xb    = (bf16_t*)(ws + 24 * MB);   //   ... reused: attn out
    bf16_t* qb    = (bf16_t*)(ws + 40 * MB);   // 16 MB  [b,h,n,64]
    bf16_t* kbuf  = (bf16_t*)(ws + 56 * MB);   // 16 MB  [b,h,m,64]
    bf16_t* vT    = (bf16_t*)(ws + 72 * MB);   // 16 MB  [b,h,64,m'] permuted

    // casts + weight transposes (one launch)
    prep<<<12288, 256, 0, stream>>>(tgt, src, tgtb, srcb,
                                    Wq, Wkv, Wo, Wq_t, Wkv_t, Wo_t);

    // Q + KV projections with fused norm/rope + V-permute epilogues (one launch)
    gemm_qkv<<<1536, 256, 0, stream>>>(tgtb, srcb, Wq_t, Wkv_t,
                                       tpos, spos, qw, kw, qb, kbuf, vT);

    // flash attention (R9/R10 double-buffered pipeline + XCD-aware swizzle)
    attn<<<1024, 256, 0, stream>>>(qb, kbuf, vT, xb);

    // output projection (fp32 out, XCD-swizzled 1-D grid)
    gemm_o<<<512, 256, 0, stream>>>(xb, Wo_t, out);
}

// Round 6
// 287.725 us; speedup vs baseline: 1.0763x; 1.0386x over previous
//
#include <hip/hip_runtime.h>

// ---------------------------------------------------------------------------
// Attention_42674795053784 : cross-attention forward on MI355X (gfx950)
// R13: attn VALU diet v2 — lsum via ones-MFMA.
//  - Row-sum of P moved off the VALU pipe: one extra MFMA per (ksm,q-tile)
//    with A = ones accumulates lsum in the matrix pipe (which has headroom),
//    deleting 32 v_add per COMPUTE and the final cross-quad shfl reduce
//    (MFMA K=32 already sums across all quads; C rows replicate the sum).
//  - Denominator now sums the SAME bf16-rounded P used in the numerator
//    (self-consistent softmax); expected output shift ~1e-4.
//  - s_setprio(1) around the pure-MFMA clusters (T5, attn-positive).
//  - prep / gemm_qkv / gemm_o unchanged from R12.
// ---------------------------------------------------------------------------

typedef __bf16 bf16_t;
typedef __bf16 bf16x8 __attribute__((ext_vector_type(8)));
typedef float  f32x4  __attribute__((ext_vector_type(4)));

#define DIMM   1024
#define NHEAD  16
#define HDIM   64
#define NB     4
#define SEQ    2048
#define NROWS  (NB * SEQ)             // 8192
#define RMS_EPS 1.1920929e-07f
#define LOG2_10000_DIV32 0.4152410118609203f
// q scale: (1/8) * log2(e) so attn can use exp2 directly
#define QSCALE 0.18033688011112042f

// async global->LDS, 16B per lane; lds dest = base + lane*16 (wave-uniform base)
__device__ __forceinline__ void async16(const bf16_t* g, bf16_t* l) {
    __builtin_amdgcn_global_load_lds(
        (const __attribute__((address_space(1))) void*)g,
        (__attribute__((address_space(3))) void*)l, 16, 0, 0);
}

// --------------------------------------------------------------------------
// prep: fp32->bf16 casts (blocks 0..8191) + 3 weight transposes (8192..12287)
// --------------------------------------------------------------------------
__global__ __launch_bounds__(256)
void prep(const float* __restrict__ tgt, const float* __restrict__ src,
          bf16_t* __restrict__ tgtb, bf16_t* __restrict__ srcb,
          const float* __restrict__ Wq, const float* __restrict__ Wkv,
          const float* __restrict__ Wo, bf16_t* __restrict__ Wq_t,
          bf16_t* __restrict__ Wkv_t, bf16_t* __restrict__ Wo_t)
{
    __shared__ float t[32][33];
    int bid = blockIdx.x;
    if (bid < 8192) {                       // elementwise cast
        const float* x;
        bf16_t* y;
        if (bid < 4096) { x = tgt; y = tgtb; }
        else            { bid -= 4096; x = src; y = srcb; }
        const size_t i = ((size_t)bid * 256 + threadIdx.x) * 8;
        float4 f0 = ((const float4*)(x + i))[0];
        float4 f1 = ((const float4*)(x + i))[1];
        bf16_t v[8];
        v[0] = (bf16_t)f0.x; v[1] = (bf16_t)f0.y; v[2] = (bf16_t)f0.z; v[3] = (bf16_t)f0.w;
        v[4] = (bf16_t)f1.x; v[5] = (bf16_t)f1.y; v[6] = (bf16_t)f1.z; v[7] = (bf16_t)f1.w;
        *(int4*)(y + i) = *(int4*)v;
        return;
    }
    bid -= 8192;                            // weight transpose
    const float* W; bf16_t* Wt; int N, nx;
    if (bid < 1024)      { W = Wq;  Wt = Wq_t;  N = 1024; nx = 32; }
    else if (bid < 3072) { bid -= 1024; W = Wkv; Wt = Wkv_t; N = 2048; nx = 64; }
    else                 { bid -= 3072; W = Wo;  Wt = Wo_t;  N = 1024; nx = 32; }
    const int K  = 1024;
    const int n0 = (bid % nx) * 32;
    const int k0 = (bid / nx) * 32;
    const int tx = threadIdx.x & 31;
    const int ty = threadIdx.x >> 5;
#pragma unroll
    for (int i = ty; i < 32; i += 8)
        t[i][tx] = W[(size_t)(k0 + i) * N + n0 + tx];
    __syncthreads();
#pragma unroll
    for (int i = ty; i < 32; i += 8)
        Wt[(size_t)(n0 + i) * K + k0 + tx] = (bf16_t)t[tx][i];
}

// --------------------------------------------------------------------------
// Shared GEMM main loop (m97-style): acc = A[128 rows] * Bt[128 rows]^T
// __shared__ tiles are DECLARED BY THE CALLER (exactly once per kernel).
// Staging offsets are 32-bit (max 16 MB) so loads lower to sbase+voffset.
// --------------------------------------------------------------------------
#define GEMM_MAIN_LOOP(A_, Bt_, K_, As, Bs)                                   \
    const int tid  = threadIdx.x;                                             \
    const int lane = tid & 63;                                                \
    const int wave = tid >> 6;                                                \
    const int wm   = (wave >> 1) * 64;                                        \
    const int wn   = (wave & 1) * 64;                                         \
    const int lr   = lane & 15;                                               \
    const int quad = lane >> 4;                                               \
    {                                                                         \
        const int srow = lane >> 3;                                           \
        const int sslot = lane & 7;                                           \
        unsigned aoff[4], boff[4];                                            \
        bf16_t *alp[4], *blp[4];                                              \
        _Pragma("unroll")                                                     \
        for (int t = 0; t < 4; ++t) {                                         \
            const int rb = wave * 32 + t * 8;                                 \
            const int r  = rb + srow;                                         \
            const int g  = sslot ^ (r & 7);                                   \
            aoff[t] = (unsigned)(bm + r) * (K_) + g * 8;                      \
            boff[t] = (unsigned)(bn + r) * (K_) + g * 8;                      \
            alp[t]  = (As) + rb * 64;                                         \
            blp[t]  = (Bs) + rb * 64;                                         \
        }                                                                     \
        for (int k0 = 0; k0 < (K_); k0 += 64) {                               \
            _Pragma("unroll")                                                 \
            for (int t = 0; t < 4; ++t) {                                     \
                async16((A_)  + (aoff[t] + k0), alp[t]);                      \
                async16((Bt_) + (boff[t] + k0), blp[t]);                      \
            }                                                                 \
            __syncthreads();                                                  \
            _Pragma("unroll")                                                 \
            for (int ks = 0; ks < 2; ++ks) {                                  \
                bf16x8 af[4], bfr[4];                                         \
                _Pragma("unroll")                                             \
                for (int i = 0; i < 4; ++i)                                   \
                    af[i] = *(const bf16x8*)&(As)[(wm + i * 16 + lr) * 64 +   \
                                (((ks * 4 + quad) ^ (lr & 7)) * 8)];          \
                _Pragma("unroll")                                             \
                for (int j = 0; j < 4; ++j)                                   \
                    bfr[j] = *(const bf16x8*)&(Bs)[(wn + j * 16 + lr) * 64 +  \
                                (((ks * 4 + quad) ^ (lr & 7)) * 8)];          \
                _Pragma("unroll")                                             \
                for (int i = 0; i < 4; ++i)                                   \
                    _Pragma("unroll")                                         \
                    for (int j = 0; j < 4; ++j)                               \
                        acc[i][j] = __builtin_amdgcn_mfma_f32_16x16x32_bf16(  \
                            af[i], bfr[j], acc[i][j], 0, 0, 0);               \
            }                                                                 \
            __syncthreads();                                                  \
        }                                                                     \
    }

// Fused per-head RMSNorm + RoPE epilogue (wave's 64 cols == one head).
__device__ __forceinline__ void norm_rope_store(
    f32x4 acc[4][4], const int* __restrict__ pos, const float* __restrict__ w,
    bf16_t* __restrict__ dstbase, int bm, int wm, int head,
    int lr, int quad, float oscale)
{
    float w0 = w[lr], w1 = w[16 + lr], w2 = w[32 + lr], w3 = w[48 + lr];
    const float invf0 = exp2f(-(float)lr * LOG2_10000_DIV32);
    const float invf1 = exp2f(-(float)(lr + 16) * LOG2_10000_DIV32);
#pragma unroll
    for (int i = 0; i < 4; ++i) {
        const int gr = bm + wm + i * 16 + quad * 4;
        int4 pos4 = *(const int4*)&pos[gr];
#pragma unroll
        for (int rg = 0; rg < 4; ++rg) {
            float x0 = acc[i][0][rg], x1 = acc[i][1][rg];
            float x2 = acc[i][2][rg], x3 = acc[i][3][rg];
            float ssum = x0 * x0 + x1 * x1 + x2 * x2 + x3 * x3;
#pragma unroll
            for (int off = 1; off < 16; off <<= 1)
                ssum += __shfl_xor(ssum, off, 64);
            const float rn = rsqrtf(ssum * (1.f / 64.f) + RMS_EPS);
            x0 *= rn * w0; x1 *= rn * w1; x2 *= rn * w2; x3 *= rn * w3;
            const float p  = (float)((&pos4.x)[rg]);
            const float a0 = p * invf0, a1 = p * invf1;
            const float s0 = __sinf(a0), c0 = __cosf(a0);
            const float s1 = __sinf(a1), c1 = __cosf(a1);
            const int row = gr + rg;
            const int bb = row >> 11, si = row & 2047;
            bf16_t* dst = dstbase +
                ((size_t)(bb * NHEAD + head) * SEQ + si) * HDIM;
            dst[lr]      = (bf16_t)((x0 * c0 - x2 * s0) * oscale);
            dst[16 + lr] = (bf16_t)((x1 * c1 - x3 * s1) * oscale);
            dst[32 + lr] = (bf16_t)((x2 * c0 + x0 * s0) * oscale);
            dst[48 + lr] = (bf16_t)((x3 * c1 + x1 * s1) * oscale);
        }
    }
}

// --------------------------------------------------------------------------
// Merged Q + KV projection.  Logical blocks 0..511: Q GEMM (fused norm+rope).
// Logical 512..1535: KV GEMM (K: norm+rope; V: m-permuted direct to vT).
// HW blockIdx is XCD-swizzled: 1536 = 8 XCDs x 192 contiguous logical blocks.
// --------------------------------------------------------------------------
__global__ __launch_bounds__(256, 4)
void gemm_qkv(const bf16_t* __restrict__ tgtb, const bf16_t* __restrict__ srcb,
              const bf16_t* __restrict__ Wq_t, const bf16_t* __restrict__ Wkv_t,
              const int* __restrict__ tpos, const int* __restrict__ spos,
              const float* __restrict__ qw, const float* __restrict__ kw,
              bf16_t* __restrict__ qb, bf16_t* __restrict__ kbuf,
              bf16_t* __restrict__ vT)
{
    __shared__ bf16_t As[128 * 64];      // single 32 KB allocation, both branches
    __shared__ bf16_t Bs[128 * 64];
    const int raw = blockIdx.x;
    const int bid = (raw & 7) * 192 + (raw >> 3);   // XCD-colocating bijection
    if (bid < 512) {                         // ---- Q projection ----
        const int bm = (bid >> 3) * 128;
        const int bn = (bid & 7) * 128;
        f32x4 acc[4][4] = {};
        GEMM_MAIN_LOOP(tgtb, Wq_t, 1024, As, Bs)
        const int head = (bn + wn) >> 6;
        norm_rope_store(acc, tpos, qw, qb, bm, wm, head, lr, quad, QSCALE);
    } else {                                 // ---- KV projection ----
        const int t2 = bid - 512;
        const int bm = (t2 >> 4) * 128;
        const int bn = (t2 & 15) * 128;
        f32x4 acc[4][4] = {};
        GEMM_MAIN_LOOP(srcb, Wkv_t, 1024, As, Bs)
        if (bn < 1024) {                     // K proj
            const int head = (bn + wn) >> 6;
            norm_rope_store(acc, spos, kw, kbuf, bm, wm, head, lr, quad, 1.0f);
        } else {                             // V proj, m-permuted to vT (R3 order)
#pragma unroll
            for (int i = 0; i < 4; ++i) {
                const int M0 = bm + wm + i * 16;
                const int b  = M0 >> 11;
                const int mB = M0 & 2047;
                const int chunkbase = mB & ~127;
                const int ksm  = (mB >> 5) & 3;
                const int bit4 = (mB >> 4) & 1;
                const int pbase = (ksm * 4 + quad) * 8 + bit4 * 4;
#pragma unroll
                for (int j = 0; j < 4; ++j) {
                    const int c = bn + wn + j * 16 + lr - 1024;
                    const int h = c >> 6;
                    const int d = c & 63;
                    bf16_t pk[4];
#pragma unroll
                    for (int rg = 0; rg < 4; ++rg) pk[rg] = (bf16_t)acc[i][j][rg];
                    bf16_t* dst = vT + ((size_t)(b * NHEAD + h) * HDIM + d) * SEQ
                                  + chunkbase + pbase;
                    *(int2*)dst = *(int2*)pk;
                }
            }
        }
    }
}

// --------------------------------------------------------------------------
// Output projection GEMM (fp32 out). 1-D grid 512 = 8 XCDs x 64, swizzled.
// --------------------------------------------------------------------------
__global__ __launch_bounds__(256, 4)
void gemm_o(const bf16_t* __restrict__ A, const bf16_t* __restrict__ Bt,
            float* __restrict__ Cp)
{
    __shared__ bf16_t As[128 * 64];
    __shared__ bf16_t Bs[128 * 64];
    const int raw = blockIdx.x;
    const int swz = (raw & 7) * 64 + (raw >> 3);    // XCD-colocating bijection
    const int bm = (swz >> 3) * 128;
    const int bn = (swz & 7) * 128;
    f32x4 acc[4][4] = {};
    GEMM_MAIN_LOOP(A, Bt, 1024, As, Bs)
#pragma unroll
    for (int i = 0; i < 4; ++i)
#pragma unroll
        for (int j = 0; j < 4; ++j) {
            const int r0 = bm + wm + i * 16 + quad * 4;
            const int c  = bn + wn + j * 16 + lr;
#pragma unroll
            for (int rg = 0; rg < 4; ++rg)
                Cp[(size_t)(r0 + rg) * 1024 + c] = acc[i][j][rg];
        }
}

// --------------------------------------------------------------------------
// Flash attention (R13): fixed-max softmax (exp2), register-resident P,
// 16x16x32 MFMAs, 4 waves x 32 q-rows, XCD-aware 1-D grid.
// KVBLK=64, double-buffered Ks/Vs, STAGE(next)->COMPUTE(cur) pipeline.
// lsum computed by ones-MFMA in the matrix pipe (kills VALU adds + the
// final cross-quad shuffle reduce); setprio(1) around MFMA clusters.
// --------------------------------------------------------------------------
__global__ __launch_bounds__(256, 4)
void attn(const bf16_t* __restrict__ q, const bf16_t* __restrict__ k,
          const bf16_t* __restrict__ vT, bf16_t* __restrict__ xo)
{
    __shared__ bf16_t Ks[2][64 * 64];     // [buf][m][d], XOR-swizzled (8 slots)
    __shared__ bf16_t Vs[2][64 * 64];     // [buf][d][m'], XOR-swizzled (8 slots)

    // swizzled decode: bid = xcd + 128*(grp&7) + 8*qx, grp>>3 == xcd
    const int bid = blockIdx.x;
    const int w   = bid >> 3;
    const int grp = (bid & 7) * 8 + (w >> 4);   // 0..63 = b*16+h
    const int q0  = (w & 15) * 128;
    const int h   = grp & 15;
    const int b   = grp >> 4;
    const int bh  = b * NHEAD + h;

    const int tid  = threadIdx.x;
    const int lane = tid & 63;
    const int wv   = tid >> 6;
    const int lr   = lane & 15;
    const int quad = lane >> 4;

    const bf16_t* kb = k  + (size_t)bh * SEQ * HDIM;
    const bf16_t* vb = vT + (size_t)bh * HDIM * SEQ;

    // Q fragments (B-operand), 2 q-tiles x 2 d-halves
    bf16x8 aq[2][2];
#pragma unroll
    for (int t = 0; t < 2; ++t) {
        const bf16_t* qp = q + ((size_t)bh * SEQ + q0 + wv * 32 + t * 16 + lr) * HDIM;
        aq[t][0] = *(const bf16x8*)(qp + quad * 8);
        aq[t][1] = *(const bf16x8*)(qp + 32 + quad * 8);
    }

    // ones vector for the lsum MFMA (A-operand)
    bf16x8 vone;
#pragma unroll
    for (int i = 0; i < 8; ++i) vone[i] = (bf16_t)1.0f;

    // cooperative staging: 2 K-DMAs + 2 V-DMAs per wave per 64-chunk.
    size_t koff[2], voff[2];
    int lbase[2];
#pragma unroll
    for (int s = 0; s < 2; ++s) {
        const int rb = wv * 16 + s * 8;
        const int r  = rb + (lane >> 3);
        const int g  = (lane & 7) ^ (r & 7);    // pre-swizzled global slot
        koff[s]  = (size_t)r * HDIM + g * 8;
        voff[s]  = (size_t)r * SEQ  + g * 8;
        lbase[s] = rb * 64;
    }

    // loop-invariant LDS read bases, both buffers (all reads = base + imm)
    const bf16_t* kbase[2][2];
    const bf16_t* vbase[2][2];
#pragma unroll
    for (int bf = 0; bf < 2; ++bf)
#pragma unroll
        for (int x = 0; x < 2; ++x) {
            const int sw = (((x * 4 + quad) ^ (lr & 7)) * 8);
            kbase[bf][x] = &Ks[bf][lr * 64 + sw];
            vbase[bf][x] = &Vs[bf][lr * 64 + sw];
        }

    f32x4 zero4 = {0.f, 0.f, 0.f, 0.f};
    f32x4 o[2][4];                        // [q-tile][d-tile]
    f32x4 oex[2];                         // [q-tile] lsum accumulator (rows replicated)
#pragma unroll
    for (int t = 0; t < 2; ++t) {
        oex[t] = zero4;
#pragma unroll
        for (int dt = 0; dt < 4; ++dt) o[t][dt] = zero4;
    }

#define STAGE(NB_, M0) do {                                                  \
    const size_t _kg = (size_t)(M0) * HDIM;                                  \
    async16(kb + _kg + koff[0], &Ks[NB_][lbase[0]]);                         \
    async16(kb + _kg + koff[1], &Ks[NB_][lbase[1]]);                         \
    async16(vb + (M0) + voff[0], &Vs[NB_][lbase[0]]);                        \
    async16(vb + (M0) + voff[1], &Vs[NB_][lbase[1]]);                        \
} while (0)

#define COMPUTE(CB) do {                                                     \
    _Pragma("unroll")                                                        \
    for (int ksm = 0; ksm < 2; ++ksm) {                                      \
        bf16x8 bp0, bp1;                                                     \
        _Pragma("unroll")                                                    \
        for (int half = 0; half < 2; ++half) {                               \
            const int mt = ksm * 2 + half;                                   \
            f32x4 s0 = zero4, s1 = zero4;                                    \
            bf16x8 ak0 = *(const bf16x8*)(kbase[CB][0] + mt * 1024);         \
            bf16x8 ak1 = *(const bf16x8*)(kbase[CB][1] + mt * 1024);         \
            __builtin_amdgcn_s_setprio(1);                                   \
            s0 = __builtin_amdgcn_mfma_f32_16x16x32_bf16(ak0, aq[0][0], s0, 0, 0, 0); \
            s1 = __builtin_amdgcn_mfma_f32_16x16x32_bf16(ak0, aq[1][0], s1, 0, 0, 0); \
            s0 = __builtin_amdgcn_mfma_f32_16x16x32_bf16(ak1, aq[0][1], s0, 0, 0, 0); \
            s1 = __builtin_amdgcn_mfma_f32_16x16x32_bf16(ak1, aq[1][1], s1, 0, 0, 0); \
            __builtin_amdgcn_s_setprio(0);                                   \
            _Pragma("unroll")                                                \
            for (int r = 0; r < 4; ++r) {                                    \
                bp0[half * 4 + r] = (bf16_t)__builtin_amdgcn_exp2f(s0[r]);   \
                bp1[half * 4 + r] = (bf16_t)__builtin_amdgcn_exp2f(s1[r]);   \
            }                                                                \
        }                                                                    \
        __builtin_amdgcn_s_setprio(1);                                       \
        _Pragma("unroll")                                                    \
        for (int dt = 0; dt < 4; ++dt) {                                     \
            bf16x8 av = *(const bf16x8*)(vbase[CB][ksm] + dt * 1024);        \
            o[0][dt] = __builtin_amdgcn_mfma_f32_16x16x32_bf16(av, bp0, o[0][dt], 0, 0, 0); \
            o[1][dt] = __builtin_amdgcn_mfma_f32_16x16x32_bf16(av, bp1, o[1][dt], 0, 0, 0); \
        }                                                                    \
        oex[0] = __builtin_amdgcn_mfma_f32_16x16x32_bf16(vone, bp0, oex[0], 0, 0, 0); \
        oex[1] = __builtin_amdgcn_mfma_f32_16x16x32_bf16(vone, bp1, oex[1], 0, 0, 0); \
        __builtin_amdgcn_s_setprio(0);                                       \
    }                                                                        \
} while (0)

    // prologue: stage chunk 0 into buf 0 (only exposed load of the kernel)
    STAGE(0, 0);
    __syncthreads();

    for (int t0 = 0; t0 < 32; t0 += 2) {
        STAGE(1, (t0 + 1) * 64);            // fly under COMPUTE(0)
        COMPUTE(0);
        __syncthreads();                    // drains long-since-landed DMAs
        STAGE(0, (((t0 + 2) & 31)) * 64);   // wrap on last iter (harmless reload)
        COMPUTE(1);
        __syncthreads();
    }

#undef STAGE
#undef COMPUTE

    // lsum: ones-MFMA output rows are all identical (full sum over m for
    // col q=lr, already summed across quads by the MFMA K-reduction).
    float inv[2];
#pragma unroll
    for (int t = 0; t < 2; ++t) inv[t] = 1.f / oex[t][0];

    // O^T C/D: row=d=quad*4+rg, col=q=lr -> 4 consecutive d: 8B stores
#pragma unroll
    for (int t = 0; t < 2; ++t)
#pragma unroll
        for (int dt = 0; dt < 4; ++dt) {
            bf16_t pk[4];
#pragma unroll
            for (int rg = 0; rg < 4; ++rg)
                pk[rg] = (bf16_t)(o[t][dt][rg] * inv[t]);
            bf16_t* dst = xo + ((size_t)b * SEQ + q0 + wv * 32 + t * 16 + lr) * DIMM
                          + h * HDIM + dt * 16 + quad * 4;
            *(int2*)dst = *(int2*)pk;
        }
}

// --------------------------------------------------------------------------
extern "C" void kernel_launch(void* const* d_in, const int* in_sizes, int n_in,
                              void* d_out, int out_size, void* d_ws, size_t ws_size,
                              hipStream_t stream)
{
    const float* tgt  = (const float*)d_in[0];
    const float* src  = (const float*)d_in[1];
    const int*   tpos = (const int*)d_in[2];
    const int*   spos = (const int*)d_in[3];
    const float* Wq   = (const float*)d_in[4];
    const float* Wkv  = (const float*)d_in[5];
    const float* Wo   = (const float*)d_in[6];
    const float* qw   = (const float*)d_in[7];
    const float* kw   = (const float*)d_in[8];
    float* out = (float*)d_out;

    // workspace layout — 88 MB with buffer reuse
    char* ws = (char*)d_ws;
    const size_t MB = 1024 * 1024;
    bf16_t* Wq_t  = (bf16_t*)(ws + 0 * MB);    //  2 MB
    bf16_t* Wkv_t = (bf16_t*)(ws + 2 * MB);    //  4 MB
    bf16_t* Wo_t  = (bf16_t*)(ws + 6 * MB);    //  2 MB
    bf16_t* tgtb  = (bf16_t*)(ws + 8 * MB);    // 16 MB
    bf16_t* srcb  = (bf16_t*)(ws + 24 * MB);   // 16 MB (dead after gemm_qkv)
    bf16_t* xb    = (bf16_t*)(ws + 24 * MB);   //   ... reused: attn out
    bf16_t* qb    = (bf16_t*)(ws + 40 * MB);   // 16 MB  [b,h,n,64]
    bf16_t* kbuf  = (bf16_t*)(ws + 56 * MB);   // 16 MB  [b,h,m,64]
    bf16_t* vT    = (bf16_t*)(ws + 72 * MB);   // 16 MB  [b,h,64,m'] permuted

    // casts + weight transposes (one launch)
    prep<<<12288, 256, 0, stream>>>(tgt, src, tgtb, srcb,
                                    Wq, Wkv, Wo, Wq_t, Wkv_t, Wo_t);

    // Q + KV projections with fused norm/rope + V-permute epilogues (one launch)
    gemm_qkv<<<1536, 256, 0, stream>>>(tgtb, srcb, Wq_t, Wkv_t,
                                       tpos, spos, qw, kw, qb, kbuf, vT);

    // flash attention (R13: ones-MFMA lsum + setprio, dbuf pipeline)
    attn<<<1024, 256, 0, stream>>>(qb, kbuf, vT, xb);

    // output projection (fp32 out, XCD-swizzled 1-D grid)
    gemm_o<<<512, 256, 0, stream>>>(xb, Wo_t, out);
}